// Round 1
// baseline (1966.063 us; speedup 1.0000x reference)
//
#include <hip/hip_runtime.h>
#include <cstdint>

#define T_STEPS 20
#define S_LEN   128
#define BATCH   32
#define HID     256
#define EMB     128
#define VOCAB   32000
#define NSTEP   (S_LEN*T_STEPS)    /* 2560 */
#define NBROWS  (NSTEP*BATCH)      /* 81920 */

typedef __bf16 bf8   __attribute__((ext_vector_type(8)));
typedef float  f32x4 __attribute__((ext_vector_type(4)));

static __device__ __forceinline__ unsigned short f2bf_u(float f){
  unsigned int u = __builtin_bit_cast(unsigned int, f);
  u = u + 0x7FFFu + ((u >> 16) & 1u);
  return (unsigned short)(u >> 16);
}

// ---------------- weight prep ----------------
__global__ void k_f32_to_bf16(const float* __restrict__ src, unsigned short* __restrict__ dst, int n4){
  int i = blockIdx.x*blockDim.x + threadIdx.x;
  if (i < n4){
    float4 v = ((const float4*)src)[i];
    ushort4 o; o.x=f2bf_u(v.x); o.y=f2bf_u(v.y); o.z=f2bf_u(v.z); o.w=f2bf_u(v.w);
    ((ushort4*)dst)[i] = o;
  }
}

// WT[k][n] = W[n][k]
__global__ void k_wT(const float* __restrict__ W, float* __restrict__ WT){
  int i = blockIdx.x*blockDim.x + threadIdx.x;   // 65536
  int n = i >> 8, k = i & 255;
  WT[k*HID + n] = W[i];
}

// Xm[s][i] = mean_b embed[x[b][s]][i]   (feeds d1 only; tolerance is huge)
__global__ void k_xm(const int* __restrict__ x, const float* __restrict__ embed, float* __restrict__ Xm){
  int s = blockIdx.x, i = threadIdx.x;  // 128 thr
  float acc = 0.f;
  for (int b=0;b<BATCH;b++){
    int tok = x[b*S_LEN + s];
    acc += embed[(size_t)tok*EMB + i];
  }
  Xm[s*EMB + i] = acc * (1.0f/32.0f);
}

// cur1[(s*B+b)][h] = fma-chain_e( embed[x[b][s]][e] * W1[h][e] ) + b1[h]  (ascending e, f32 FMA)
__global__ __launch_bounds__(256) void k_cur1(const int* __restrict__ x, const float* __restrict__ embed,
                                              const float* __restrict__ W1, const float* __restrict__ b1,
                                              float* __restrict__ cur1){
  __shared__ float xe[BATCH*EMB];  // [b][e]
  int s = blockIdx.x, t = threadIdx.x;
  for (int i=t; i<BATCH*EMB/4; i+=256){
    int b = i >> 5, e4 = i & 31;
    int tok = x[b*S_LEN + s];
    ((float4*)xe)[i] = ((const float4*)(embed + (size_t)tok*EMB))[e4];
  }
  __syncthreads();
  int h = t;
  float acc[BATCH];
  #pragma unroll
  for (int b=0;b<BATCH;b++) acc[b]=0.f;
  for (int ec=0; ec<4; ec++){
    float wd[32];
    #pragma unroll
    for (int e4=0;e4<8;e4++){
      float4 w = *(const float4*)(W1 + (size_t)h*EMB + ec*32 + e4*4);
      wd[e4*4+0]=w.x; wd[e4*4+1]=w.y; wd[e4*4+2]=w.z; wd[e4*4+3]=w.w;
    }
    #pragma unroll
    for (int b=0;b<BATCH;b++){
      #pragma unroll
      for (int e=0;e<32;e++)
        acc[b] = fmaf(xe[b*EMB + ec*32 + e], wd[e], acc[b]);   // ascending k, single chain
    }
  }
  float bi = b1[h];
  #pragma unroll
  for (int b=0;b<BATCH;b++)
    cur1[(size_t)(s*BATCH + b)*HID + h] = __fadd_rn(acc[b], bi);
}

// ---------------- LIF scans: np-exact f32 op order (mul, add, sub; no FMA) ----------------
__global__ __launch_bounds__(64) void k_scan1(const float* __restrict__ cur1, float* __restrict__ rec,
                                              float* __restrict__ memout){
  int bid = blockIdx.x; int b = bid >> 2; int hq = bid & 3;
  int h = hq*64 + threadIdx.x;
  const int strN = BATCH*HID;
  const float* cp = cur1 + b*HID + h;
  float* rp = rec + b*HID + h;
  float mem = 0.f;
  float c = cp[0];
  for (int s=0; s<S_LEN; s++){
    float cn = (s+1 < S_LEN) ? cp[(size_t)(s+1)*strN] : 0.f;   // prefetch next token
    #pragma unroll
    for (int t=0;t<T_STEPS;t++){
      float reset = (mem > 1.0f) ? 1.0f : 0.0f;
      float tm = __fmul_rn(0.85f, mem);
      tm = __fadd_rn(tm, c);
      mem = __fsub_rn(tm, reset);
      rp[(size_t)(s*T_STEPS + t)*strN] = (mem > 1.0f) ? 1.0f : 0.0f;
    }
    c = cn;
  }
  memout[b*HID + h] = mem;
}

// layers 2/3: cur per step (bias already folded, rounded, in GEMM); POOL emits bf16 pooled means
template<bool POOL>
__global__ __launch_bounds__(64) void k_scan23(const float* __restrict__ cur,
                                               float* __restrict__ rec, float* __restrict__ memout,
                                               unsigned short* __restrict__ pooled){
  int bid = blockIdx.x; int b = bid >> 2; int hq = bid & 3;
  int h = hq*64 + threadIdx.x;
  const int strN = BATCH*HID;
  const float* cp = cur + b*HID + h;
  float* rp = rec + b*HID + h;
  unsigned short* pp = POOL ? (pooled + (size_t)b*S_LEN*HID + h) : nullptr;
  float mem = 0.f;
  float ps = 0.f;
  int tc = 0, sTok = 0;
  float cA[16], cB[16];

  auto step = [&](float c, int n){
    float reset = (mem > 1.0f) ? 1.0f : 0.0f;
    float tm = __fmul_rn(0.85f, mem);
    tm = __fadd_rn(tm, c);
    mem = __fsub_rn(tm, reset);
    float spk = (mem > 1.0f) ? 1.f : 0.f;
    rp[(size_t)n*strN] = spk;
    if constexpr (POOL){
      ps += spk;                       // exact integer count <= 20
      if (++tc == T_STEPS){
        pp[(size_t)sTok*HID] = f2bf_u(__fdiv_rn(ps, 20.0f));   // np mean = sum/20, correctly rounded
        ps = 0.f; tc = 0; ++sTok;
      }
    }
  };

  #pragma unroll
  for (int j=0;j<16;j++) cA[j] = cp[(size_t)j*strN];
  for (int n0=0; n0<NSTEP; n0+=32){
    #pragma unroll
    for (int j=0;j<16;j++) cB[j] = cp[(size_t)(n0+16+j)*strN];
    #pragma unroll
    for (int j=0;j<16;j++) step(cA[j], n0+j);
    if (n0+32 < NSTEP){
      #pragma unroll
      for (int j=0;j<16;j++) cA[j] = cp[(size_t)(n0+32+j)*strN];
    }
    #pragma unroll
    for (int j=0;j<16;j++) step(cB[j], n0+16+j);
  }
  memout[b*HID + h] = mem;
}

// ---------------- np/BLAS-exact f32 GEMM ----------------
// cur[m][n] = ( fma-chain_{k=0..255} spk[m][k]*W[n][k] )  +rn bias[n]
// Bit-identical op order to before (single ascending-k FMA chain per element).
// New data movement: A (spk) staged in LDS via coalesced float4 loads (pad-36
// rows -> ~2-way bank access, free); each thread owns one m-row and 32 n's;
// WT rows remain wave-uniform -> SGPR s_load. Grid x = n-block (8) fastest so
// the 8 blocks sharing an A-panel are dispatch-adjacent (L2/L3 hit).
__global__ __launch_bounds__(256) void k_gemm_f32(const float* __restrict__ spk,
                                                  const float* __restrict__ WT,   // [256][256] transposed
                                                  const float* __restrict__ bias,
                                                  float* __restrict__ curo){
  __shared__ float As[256*36];        // 256 rows x 32 k, padded to 36 floats
  int m0 = blockIdx.y * 256;
  int n0 = blockIdx.x * 32;
  int t  = threadIdx.x;
  float acc[32];
  #pragma unroll
  for (int n=0;n<32;n++) acc[n]=0.f;

  for (int kc=0; kc<8; kc++){
    __syncthreads();                  // readers of previous tile done
    #pragma unroll
    for (int i=0;i<8;i++){
      int id = t + i*256;             // 2048 float4 = 256 rows x 32 k
      int r = id >> 3, c4 = id & 7;   // 8 lanes per row -> 128 B coalesced
      float4 v = *(const float4*)(spk + (size_t)(m0 + r)*HID + kc*32 + c4*4);
      *(float4*)(As + r*36 + c4*4) = v;
    }
    __syncthreads();
    const float* wrow = WT + (size_t)(kc*32)*HID + n0;
    #pragma unroll
    for (int g=0; g<8; g++){
      float4 sv4 = *(const float4*)(As + t*36 + g*4);   // own row, 4 k's, b128
      #pragma unroll
      for (int j=0;j<4;j++){
        float sv = (j==0)?sv4.x:(j==1)?sv4.y:(j==2)?sv4.z:sv4.w;
        const float* wt = wrow + (size_t)(g*4+j)*HID;   // wave-uniform -> s_load
        #pragma unroll
        for (int n=0;n<32;n++)
          acc[n] = fmaf(sv, wt[n], acc[n]);             // ascending k, single chain
      }
    }
  }
  float* op = curo + (size_t)(m0 + t)*HID + n0;
  #pragma unroll
  for (int n=0;n<32;n++) op[n] = __fadd_rn(acc[n], bias[n0+n]);
}

// ---------------- bf16 MFMA out-GEMM: out[4096][32000] = pooled[4096][256] @ Wout^T + bout ----------------
template<bool BF16B>
__global__ __launch_bounds__(256,2) void k_gemm_out(const unsigned short* __restrict__ Abf,
                                                    const unsigned short* __restrict__ Bbf,
                                                    const float* __restrict__ Bf32,
                                                    const float* __restrict__ bout,
                                                    float* __restrict__ outp){
  __shared__ unsigned short As[128*72];
  __shared__ unsigned short Bs[128*72];
  int bid = blockIdx.x;
  int ntile = bid >> 5;
  int mtile = bid & 31;
  int m0 = mtile*128, n0 = ntile*128;
  int tid = threadIdx.x;
  int lane = tid & 63, wave = tid >> 6;
  int wm = wave >> 1, wn = wave & 1;
  int lm = lane & 15, quad = lane >> 4;
  f32x4 acc[4][4] = {};

  for (int kt=0; kt<4; kt++){
    int k0 = kt*64;
    uint4 avb[4];
    #pragma unroll
    for (int i=0;i<4;i++){
      int id = tid + i*256; int r = id>>3, c16 = id&7;
      avb[i] = *(const uint4*)(Abf + (size_t)(m0 + r)*HID + k0 + c16*8);
    }
    uint4 bvb[4]; float4 bvf[8];
    if (BF16B){
      #pragma unroll
      for (int i=0;i<4;i++){
        int id = tid + i*256; int r = id>>3, c16 = id&7;
        bvb[i] = *(const uint4*)(Bbf + (size_t)(n0 + r)*HID + k0 + c16*8);
      }
    } else {
      #pragma unroll
      for (int i=0;i<8;i++){
        int id = tid + i*256; int r = id>>4, c4 = id&15;
        bvf[i] = *(const float4*)(Bf32 + (size_t)(n0 + r)*HID + k0 + c4*4);
      }
    }
    __syncthreads();
    #pragma unroll
    for (int i=0;i<4;i++){
      int id = tid + i*256; int r = id>>3, c16 = id&7;
      *(uint4*)(As + r*72 + c16*8) = avb[i];
    }
    if (BF16B){
      #pragma unroll
      for (int i=0;i<4;i++){
        int id = tid + i*256; int r = id>>3, c16 = id&7;
        *(uint4*)(Bs + r*72 + c16*8) = bvb[i];
      }
    } else {
      #pragma unroll
      for (int i=0;i<8;i++){
        int id = tid + i*256; int r = id>>4, c4 = id&15;
        ushort4 o; o.x=f2bf_u(bvf[i].x); o.y=f2bf_u(bvf[i].y); o.z=f2bf_u(bvf[i].z); o.w=f2bf_u(bvf[i].w);
        *(ushort4*)(Bs + r*72 + c4*4) = o;
      }
    }
    __syncthreads();
    bf8 af[4][2], bfr[4][2];
    #pragma unroll
    for (int mt=0;mt<4;mt++)
      #pragma unroll
      for (int kk=0;kk<2;kk++)
        af[mt][kk] = *(const bf8*)(As + (wm*64 + mt*16 + lm)*72 + kk*32 + quad*8);
    #pragma unroll
    for (int nt=0;nt<4;nt++)
      #pragma unroll
      for (int kk=0;kk<2;kk++)
        bfr[nt][kk] = *(const bf8*)(Bs + (wn*64 + nt*16 + lm)*72 + kk*32 + quad*8);
    #pragma unroll
    for (int mt=0;mt<4;mt++)
      #pragma unroll
      for (int nt=0;nt<4;nt++){
        acc[mt][nt] = __builtin_amdgcn_mfma_f32_16x16x32_bf16(af[mt][0], bfr[nt][0], acc[mt][nt], 0,0,0);
        acc[mt][nt] = __builtin_amdgcn_mfma_f32_16x16x32_bf16(af[mt][1], bfr[nt][1], acc[mt][nt], 0,0,0);
      }
    __syncthreads();
  }
  #pragma unroll
  for (int nt=0;nt<4;nt++){
    int v = n0 + wn*64 + nt*16 + lm;
    float bo = bout[v];
    #pragma unroll
    for (int mt=0;mt<4;mt++)
      #pragma unroll
      for (int rr=0;rr<4;rr++){
        int r = m0 + wm*64 + mt*16 + quad*4 + rr;
        outp[(size_t)r*VOCAB + v] = acc[mt][nt][rr] + bo;
      }
  }
}

// ---------------- STDP ----------------
__global__ void k_mmean(const float* __restrict__ rec, float* __restrict__ M){
  int m = blockIdx.x, o = threadIdx.x;
  int s = m / 7, j = m - 7*s;
  int n = s*T_STEPS + j*3;
  const float* rp = rec + (size_t)n*BATCH*HID + o;
  float acc = 0.f;
  #pragma unroll
  for (int b=0;b<BATCH;b++) acc += rp[b*HID];
  M[m*HID + o] = acc * (1.0f/32.0f);   // exact: integer count / 32
}

__global__ void k_d1(const float* __restrict__ M1, const float* __restrict__ Xm, float* __restrict__ d1){
  __shared__ float col[896];
  int o = blockIdx.x, i = threadIdx.x; // 128 thr
  for (int m=i; m<896; m+=128) col[m] = M1[m*HID + o];
  __syncthreads();
  float acc = 0.f;
  for (int s=0;s<S_LEN;s++){
    float xv = Xm[s*EMB + i];
    float cs = 0.f;
    #pragma unroll
    for (int j=0;j<7;j++) cs += col[s*7+j];
    acc += cs * xv;
  }
  d1[o*EMB + i] = -1.5e-5f * acc;
}

__global__ void k_d23(const float* __restrict__ Mpost, const float* __restrict__ Mpre, float* __restrict__ d){
  __shared__ float col[896];
  int o = blockIdx.x, i = threadIdx.x; // 256 thr
  for (int m=i; m<896; m+=256) col[m] = Mpost[m*HID + o];
  __syncthreads();
  float acc = 0.f;
  for (int m=0;m<896;m++) acc += col[m] * Mpre[m*HID + i];
  d[o*HID + i] = -1.5e-5f * acc;
}

// ---------------- launch ----------------
extern "C" void kernel_launch(void* const* d_in, const int* in_sizes, int n_in,
                              void* d_out, int out_size, void* d_ws, size_t ws_size,
                              hipStream_t stream){
  const int*   x     = (const int*)d_in[0];
  const float* embed = (const float*)d_in[1];
  const float* W1    = (const float*)d_in[2];
  const float* b1    = (const float*)d_in[3];
  const float* W2    = (const float*)d_in[4];
  const float* b2    = (const float*)d_in[5];
  const float* W3    = (const float*)d_in[6];
  const float* b3    = (const float*)d_in[7];
  const float* Wout  = (const float*)d_in[8];
  const float* bout  = (const float*)d_in[9];
  float* out = (float*)d_out;

  // output regions (float offsets)
  float* mem1 = out + 131072000;
  float* mem2 = out + 131080192;
  float* mem3 = out + 131088384;
  float* d1   = out + 131096576;
  float* d2   = out + 131129344;
  float* d3   = out + 131194880;
  float* rec1 = out + 131260416;
  float* rec2 = out + 152231936;
  float* rec3 = out + 173203456;

  // scratch carved from the out[B,S,V] region (dead until final GEMM overwrites it)
  float* curbuf = out + 0;                       // 81920*256 f32
  float* cur1   = out + 20971520;                // 4096*256
  float* Xm     = out + 22020096;                // 16384
  float* M1     = out + 22036480;                // 229376
  float* M2     = out + 22265856;
  float* M3     = out + 22495232;
  float* WT2    = out + 22724608;                // 65536
  float* WT3    = out + 22790144;                // end 22855680 < 131072000

  // ws: pooled bf16 (2 MB) + optional Wout bf16 (16.4 MB)
  unsigned short* pooled = (unsigned short*)d_ws;
  bool haveWoutBf = ws_size >= (size_t)(2097152 + 16384000);
  unsigned short* woutbf = (unsigned short*)((char*)d_ws + 2097152);

  if (haveWoutBf)
    k_f32_to_bf16<<<8000,256,0,stream>>>(Wout, woutbf, VOCAB*HID/4);
  k_wT<<<256,256,0,stream>>>(W2, WT2);
  k_wT<<<256,256,0,stream>>>(W3, WT3);
  k_xm<<<128,128,0,stream>>>(x, embed, Xm);
  k_cur1<<<128,256,0,stream>>>(x, embed, W1, b1, cur1);

  k_scan1<<<128,64,0,stream>>>(cur1, rec1, mem1);
  k_gemm_f32<<<dim3(8,320),256,0,stream>>>(rec1, WT2, b2, curbuf);
  k_scan23<false><<<128,64,0,stream>>>(curbuf, rec2, mem2, nullptr);
  k_gemm_f32<<<dim3(8,320),256,0,stream>>>(rec2, WT3, b3, curbuf);
  k_scan23<true><<<128,64,0,stream>>>(curbuf, rec3, mem3, pooled);

  k_mmean<<<896,256,0,stream>>>(rec1, M1);
  k_mmean<<<896,256,0,stream>>>(rec2, M2);
  k_mmean<<<896,256,0,stream>>>(rec3, M3);
  k_d1<<<256,128,0,stream>>>(M1, Xm, d1);
  k_d23<<<256,256,0,stream>>>(M2, M1, d2);
  k_d23<<<256,256,0,stream>>>(M3, M2, d3);

  if (haveWoutBf)
    k_gemm_out<true ><<<8000,256,0,stream>>>(pooled, woutbf, nullptr, bout, out);
  else
    k_gemm_out<false><<<8000,256,0,stream>>>(pooled, nullptr, Wout,  bout, out);
}

// Round 2
// 1921.619 us; speedup vs baseline: 1.0231x; 1.0231x over previous
//
#include <hip/hip_runtime.h>
#include <cstdint>

#define T_STEPS 20
#define S_LEN   128
#define BATCH   32
#define HID     256
#define EMB     128
#define VOCAB   32000
#define NSTEP   (S_LEN*T_STEPS)    /* 2560 */
#define NBROWS  (NSTEP*BATCH)      /* 81920 */

typedef __bf16 bf8   __attribute__((ext_vector_type(8)));
typedef float  f32x4 __attribute__((ext_vector_type(4)));

static __device__ __forceinline__ unsigned short f2bf_u(float f){
  unsigned int u = __builtin_bit_cast(unsigned int, f);
  u = u + 0x7FFFu + ((u >> 16) & 1u);
  return (unsigned short)(u >> 16);
}

// ---------------- fused prep: bf16(Wout) | W2^T | W3^T | Xm ----------------
// blk layout: [0,8000) bf16 convert, [8000,8256) WT2, [8256,8512) WT3, [8512,8576) Xm
__global__ __launch_bounds__(256) void k_prep(const float* __restrict__ Wout, unsigned short* __restrict__ woutbf,
                                              const float* __restrict__ W2, float* __restrict__ WT2,
                                              const float* __restrict__ W3, float* __restrict__ WT3,
                                              const int* __restrict__ x, const float* __restrict__ embed,
                                              float* __restrict__ Xm, int base){
  int blk = blockIdx.x + base;
  int t = threadIdx.x;
  if (blk < 8000){
    int i = blk*256 + t;                 // < 2048000 exactly
    float4 v = ((const float4*)Wout)[i];
    ushort4 o; o.x=f2bf_u(v.x); o.y=f2bf_u(v.y); o.z=f2bf_u(v.z); o.w=f2bf_u(v.w);
    ((ushort4*)woutbf)[i] = o;
  } else if (blk < 8256){
    int i = (blk-8000)*256 + t;          // 65536
    int n = i >> 8, k = i & 255;
    WT2[k*HID + n] = W2[i];
  } else if (blk < 8512){
    int i = (blk-8256)*256 + t;
    int n = i >> 8, k = i & 255;
    WT3[k*HID + n] = W3[i];
  } else {
    int s = (blk-8512)*2 + (t >> 7);     // 64 blocks x 2 s
    int i = t & 127;
    float acc = 0.f;
    for (int b=0;b<BATCH;b++){
      int tok = x[b*S_LEN + s];
      acc += embed[(size_t)tok*EMB + i];
    }
    Xm[s*EMB + i] = acc * (1.0f/32.0f);
  }
}

// cur1[(s*B+b)][h] = fma-chain_e( embed[x[b][s]][e] * W1[h][e] ) + b1[h]  (ascending e, f32 FMA)
__global__ __launch_bounds__(256) void k_cur1(const int* __restrict__ x, const float* __restrict__ embed,
                                              const float* __restrict__ W1, const float* __restrict__ b1,
                                              float* __restrict__ cur1){
  __shared__ float xe[BATCH*EMB];  // [b][e]
  int s = blockIdx.x, t = threadIdx.x;
  for (int i=t; i<BATCH*EMB/4; i+=256){
    int b = i >> 5, e4 = i & 31;
    int tok = x[b*S_LEN + s];
    ((float4*)xe)[i] = ((const float4*)(embed + (size_t)tok*EMB))[e4];
  }
  __syncthreads();
  int h = t;
  float acc[BATCH];
  #pragma unroll
  for (int b=0;b<BATCH;b++) acc[b]=0.f;
  for (int ec=0; ec<4; ec++){
    float wd[32];
    #pragma unroll
    for (int e4=0;e4<8;e4++){
      float4 w = *(const float4*)(W1 + (size_t)h*EMB + ec*32 + e4*4);
      wd[e4*4+0]=w.x; wd[e4*4+1]=w.y; wd[e4*4+2]=w.z; wd[e4*4+3]=w.w;
    }
    #pragma unroll
    for (int b=0;b<BATCH;b++){
      #pragma unroll
      for (int e=0;e<32;e++)
        acc[b] = fmaf(xe[b*EMB + ec*32 + e], wd[e], acc[b]);   // ascending k, single chain
    }
  }
  float bi = b1[h];
  #pragma unroll
  for (int b=0;b<BATCH;b++)
    cur1[(size_t)(s*BATCH + b)*HID + h] = __fadd_rn(acc[b], bi);
}

// ---------------- LIF scans: np-exact f32 op order (mul, add, sub; no FMA) ----------------
__global__ __launch_bounds__(64) void k_scan1(const float* __restrict__ cur1, float* __restrict__ rec,
                                              float* __restrict__ memout){
  int bid = blockIdx.x; int b = bid >> 2; int hq = bid & 3;
  int h = hq*64 + threadIdx.x;
  const int strN = BATCH*HID;
  const float* cp = cur1 + b*HID + h;
  float* rp = rec + b*HID + h;
  float mem = 0.f;
  float c = cp[0];
  for (int s=0; s<S_LEN; s++){
    float cn = (s+1 < S_LEN) ? cp[(size_t)(s+1)*strN] : 0.f;   // prefetch next token
    #pragma unroll
    for (int t=0;t<T_STEPS;t++){
      float reset = (mem > 1.0f) ? 1.0f : 0.0f;
      float tm = __fmul_rn(0.85f, mem);
      tm = __fadd_rn(tm, c);
      mem = __fsub_rn(tm, reset);
      rp[(size_t)(s*T_STEPS + t)*strN] = (mem > 1.0f) ? 1.0f : 0.0f;
    }
    c = cn;
  }
  memout[b*HID + h] = mem;
}

// layers 2/3: cur per step (bias already folded, rounded, in GEMM); POOL emits bf16 pooled means
template<bool POOL>
__global__ __launch_bounds__(64) void k_scan23(const float* __restrict__ cur,
                                               float* __restrict__ rec, float* __restrict__ memout,
                                               unsigned short* __restrict__ pooled){
  int bid = blockIdx.x; int b = bid >> 2; int hq = bid & 3;
  int h = hq*64 + threadIdx.x;
  const int strN = BATCH*HID;
  const float* cp = cur + b*HID + h;
  float* rp = rec + b*HID + h;
  unsigned short* pp = POOL ? (pooled + (size_t)b*S_LEN*HID + h) : nullptr;
  float mem = 0.f;
  float ps = 0.f;
  int tc = 0, sTok = 0;
  float cA[16], cB[16];

  auto step = [&](float c, int n){
    float reset = (mem > 1.0f) ? 1.0f : 0.0f;
    float tm = __fmul_rn(0.85f, mem);
    tm = __fadd_rn(tm, c);
    mem = __fsub_rn(tm, reset);
    float spk = (mem > 1.0f) ? 1.f : 0.f;
    rp[(size_t)n*strN] = spk;
    if constexpr (POOL){
      ps += spk;                       // exact integer count <= 20
      if (++tc == T_STEPS){
        pp[(size_t)sTok*HID] = f2bf_u(__fdiv_rn(ps, 20.0f));   // np mean = sum/20, correctly rounded
        ps = 0.f; tc = 0; ++sTok;
      }
    }
  };

  #pragma unroll
  for (int j=0;j<16;j++) cA[j] = cp[(size_t)j*strN];
  for (int n0=0; n0<NSTEP; n0+=32){
    #pragma unroll
    for (int j=0;j<16;j++) cB[j] = cp[(size_t)(n0+16+j)*strN];
    #pragma unroll
    for (int j=0;j<16;j++) step(cA[j], n0+j);
    if (n0+32 < NSTEP){
      #pragma unroll
      for (int j=0;j<16;j++) cA[j] = cp[(size_t)(n0+32+j)*strN];
    }
    #pragma unroll
    for (int j=0;j<16;j++) step(cB[j], n0+16+j);
  }
  memout[b*HID + h] = mem;
}

// ---------------- np/BLAS-exact f32 GEMM ----------------
// cur[m][n] = ( fma-chain_{k=0..255} spk[m][k]*W[n][k] )  +rn bias[n]
// Bit-identical op order (single ascending-k FMA chain per element).
// XCD-ownership swizzle: x=bid&7 (XCD under %8 round-robin), i=bid>>3;
// w = x*320+i gives XCD x the contiguous m-panel range [40x,40x+40) with the
// 8 n-blocks of each panel consecutive -> A-panel fetched by ONE XCD-L2 only
// (live working set ~2 MB < 4 MB L2), instead of every panel through all 8.
__global__ __launch_bounds__(256) void k_gemm_f32(const float* __restrict__ spk,
                                                  const float* __restrict__ WT,   // [256][256] transposed
                                                  const float* __restrict__ bias,
                                                  float* __restrict__ curo){
  __shared__ float As[256*36];        // 256 rows x 32 k, padded to 36 floats
  int bid = blockIdx.x;               // 2560
  int x = bid & 7, i = bid >> 3;
  int w = x*320 + i;
  int m0 = (w >> 3) * 256;
  int n0 = (w & 7) * 32;
  int t  = threadIdx.x;
  float acc[32];
  #pragma unroll
  for (int n=0;n<32;n++) acc[n]=0.f;

  for (int kc=0; kc<8; kc++){
    __syncthreads();                  // readers of previous tile done
    #pragma unroll
    for (int j=0;j<8;j++){
      int id = t + j*256;             // 2048 float4 = 256 rows x 32 k
      int r = id >> 3, c4 = id & 7;   // 8 lanes per row -> 128 B coalesced
      float4 v = *(const float4*)(spk + (size_t)(m0 + r)*HID + kc*32 + c4*4);
      *(float4*)(As + r*36 + c4*4) = v;
    }
    __syncthreads();
    const float* wrow = WT + (size_t)(kc*32)*HID + n0;
    #pragma unroll
    for (int g=0; g<8; g++){
      float4 sv4 = *(const float4*)(As + t*36 + g*4);   // own row, 4 k's, b128
      #pragma unroll
      for (int j=0;j<4;j++){
        float sv = (j==0)?sv4.x:(j==1)?sv4.y:(j==2)?sv4.z:sv4.w;
        const float* wt = wrow + (size_t)(g*4+j)*HID;   // wave-uniform -> s_load
        #pragma unroll
        for (int n=0;n<32;n++)
          acc[n] = fmaf(sv, wt[n], acc[n]);             // ascending k, single chain
      }
    }
  }
  float* op = curo + (size_t)(m0 + t)*HID + n0;
  #pragma unroll
  for (int n=0;n<32;n++) op[n] = __fadd_rn(acc[n], bias[n0+n]);
}

// ---------------- bf16 MFMA out-GEMM: out[4096][32000] = pooled[4096][256] @ Wout^T + bout ----------------
// XCD swizzle: x=bid&7, i=bid>>3, w=x*1000+i -> each XCD owns a contiguous
// ntile range; the 32 m-sharers of each B-panel stay w-consecutive AND on one
// XCD -> B fetched ~once per panel (16 MB total vs 128 MB). C stored with
// non-temporal hint (written once, never read) to keep L2 for A/B panels.
template<bool BF16B>
__global__ __launch_bounds__(256,2) void k_gemm_out(const unsigned short* __restrict__ Abf,
                                                    const unsigned short* __restrict__ Bbf,
                                                    const float* __restrict__ Bf32,
                                                    const float* __restrict__ bout,
                                                    float* __restrict__ outp){
  __shared__ unsigned short As[128*72];
  __shared__ unsigned short Bs[128*72];
  int bid = blockIdx.x;               // 8000
  int xc = bid & 7, ib = bid >> 3;
  int w = xc*1000 + ib;
  int ntile = w >> 5;
  int mtile = w & 31;
  int m0 = mtile*128, n0 = ntile*128;
  int tid = threadIdx.x;
  int lane = tid & 63, wave = tid >> 6;
  int wm = wave >> 1, wn = wave & 1;
  int lm = lane & 15, quad = lane >> 4;
  f32x4 acc[4][4] = {};

  for (int kt=0; kt<4; kt++){
    int k0 = kt*64;
    uint4 avb[4];
    #pragma unroll
    for (int i=0;i<4;i++){
      int id = tid + i*256; int r = id>>3, c16 = id&7;
      avb[i] = *(const uint4*)(Abf + (size_t)(m0 + r)*HID + k0 + c16*8);
    }
    uint4 bvb[4]; float4 bvf[8];
    if (BF16B){
      #pragma unroll
      for (int i=0;i<4;i++){
        int id = tid + i*256; int r = id>>3, c16 = id&7;
        bvb[i] = *(const uint4*)(Bbf + (size_t)(n0 + r)*HID + k0 + c16*8);
      }
    } else {
      #pragma unroll
      for (int i=0;i<8;i++){
        int id = tid + i*256; int r = id>>4, c4 = id&15;
        bvf[i] = *(const float4*)(Bf32 + (size_t)(n0 + r)*HID + k0 + c4*4);
      }
    }
    __syncthreads();
    #pragma unroll
    for (int i=0;i<4;i++){
      int id = tid + i*256; int r = id>>3, c16 = id&7;
      *(uint4*)(As + r*72 + c16*8) = avb[i];
    }
    if (BF16B){
      #pragma unroll
      for (int i=0;i<4;i++){
        int id = tid + i*256; int r = id>>3, c16 = id&7;
        *(uint4*)(Bs + r*72 + c16*8) = bvb[i];
      }
    } else {
      #pragma unroll
      for (int i=0;i<8;i++){
        int id = tid + i*256; int r = id>>4, c4 = id&15;
        ushort4 o; o.x=f2bf_u(bvf[i].x); o.y=f2bf_u(bvf[i].y); o.z=f2bf_u(bvf[i].z); o.w=f2bf_u(bvf[i].w);
        *(ushort4*)(Bs + r*72 + c4*4) = o;
      }
    }
    __syncthreads();
    bf8 af[4][2], bfr[4][2];
    #pragma unroll
    for (int mt=0;mt<4;mt++)
      #pragma unroll
      for (int kk=0;kk<2;kk++)
        af[mt][kk] = *(const bf8*)(As + (wm*64 + mt*16 + lm)*72 + kk*32 + quad*8);
    #pragma unroll
    for (int nt=0;nt<4;nt++)
      #pragma unroll
      for (int kk=0;kk<2;kk++)
        bfr[nt][kk] = *(const bf8*)(Bs + (wn*64 + nt*16 + lm)*72 + kk*32 + quad*8);
    #pragma unroll
    for (int mt=0;mt<4;mt++)
      #pragma unroll
      for (int nt=0;nt<4;nt++){
        acc[mt][nt] = __builtin_amdgcn_mfma_f32_16x16x32_bf16(af[mt][0], bfr[nt][0], acc[mt][nt], 0,0,0);
        acc[mt][nt] = __builtin_amdgcn_mfma_f32_16x16x32_bf16(af[mt][1], bfr[nt][1], acc[mt][nt], 0,0,0);
      }
    __syncthreads();
  }
  #pragma unroll
  for (int nt=0;nt<4;nt++){
    int v = n0 + wn*64 + nt*16 + lm;
    float bo = bout[v];
    #pragma unroll
    for (int mt=0;mt<4;mt++)
      #pragma unroll
      for (int rr=0;rr<4;rr++){
        int r = m0 + wm*64 + mt*16 + quad*4 + rr;
        __builtin_nontemporal_store(acc[mt][nt][rr] + bo, &outp[(size_t)r*VOCAB + v]);
      }
  }
}

// ---------------- STDP ----------------
__global__ void k_mmean(const float* __restrict__ rec, float* __restrict__ M){
  int m = blockIdx.x, o = threadIdx.x;
  int s = m / 7, j = m - 7*s;
  int n = s*T_STEPS + j*3;
  const float* rp = rec + (size_t)n*BATCH*HID + o;
  float acc = 0.f;
  #pragma unroll
  for (int b=0;b<BATCH;b++) acc += rp[b*HID];
  M[m*HID + o] = acc * (1.0f/32.0f);   // exact: integer count / 32
}

__global__ void k_d1(const float* __restrict__ M1, const float* __restrict__ Xm, float* __restrict__ d1){
  __shared__ float col[896];
  int o = blockIdx.x, i = threadIdx.x; // 128 thr
  for (int m=i; m<896; m+=128) col[m] = M1[m*HID + o];
  __syncthreads();
  float acc = 0.f;
  for (int s=0;s<S_LEN;s++){
    float xv = Xm[s*EMB + i];
    float cs = 0.f;
    #pragma unroll
    for (int j=0;j<7;j++) cs += col[s*7+j];
    acc += cs * xv;
  }
  d1[o*EMB + i] = -1.5e-5f * acc;
}

__global__ void k_d23(const float* __restrict__ Mpost, const float* __restrict__ Mpre, float* __restrict__ d){
  __shared__ float col[896];
  int o = blockIdx.x, i = threadIdx.x; // 256 thr
  for (int m=i; m<896; m+=256) col[m] = Mpost[m*HID + o];
  __syncthreads();
  float acc = 0.f;
  for (int m=0;m<896;m++) acc += col[m] * Mpre[m*HID + i];
  d[o*HID + i] = -1.5e-5f * acc;
}

// ---------------- launch ----------------
extern "C" void kernel_launch(void* const* d_in, const int* in_sizes, int n_in,
                              void* d_out, int out_size, void* d_ws, size_t ws_size,
                              hipStream_t stream){
  const int*   x     = (const int*)d_in[0];
  const float* embed = (const float*)d_in[1];
  const float* W1    = (const float*)d_in[2];
  const float* b1    = (const float*)d_in[3];
  const float* W2    = (const float*)d_in[4];
  const float* b2    = (const float*)d_in[5];
  const float* W3    = (const float*)d_in[6];
  const float* b3    = (const float*)d_in[7];
  const float* Wout  = (const float*)d_in[8];
  const float* bout  = (const float*)d_in[9];
  float* out = (float*)d_out;

  // output regions (float offsets)
  float* mem1 = out + 131072000;
  float* mem2 = out + 131080192;
  float* mem3 = out + 131088384;
  float* d1   = out + 131096576;
  float* d2   = out + 131129344;
  float* d3   = out + 131194880;
  float* rec1 = out + 131260416;
  float* rec2 = out + 152231936;
  float* rec3 = out + 173203456;

  // scratch carved from the out[B,S,V] region (dead until final GEMM overwrites it)
  float* curbuf = out + 0;                       // 81920*256 f32
  float* cur1   = out + 20971520;                // 4096*256
  float* Xm     = out + 22020096;                // 16384
  float* M1     = out + 22036480;                // 229376
  float* M2     = out + 22265856;
  float* M3     = out + 22495232;
  float* WT2    = out + 22724608;                // 65536
  float* WT3    = out + 22790144;                // end 22855680 < 131072000

  // ws: pooled bf16 (2 MB) + optional Wout bf16 (16.4 MB)
  unsigned short* pooled = (unsigned short*)d_ws;
  bool haveWoutBf = ws_size >= (size_t)(2097152 + 16384000);
  unsigned short* woutbf = (unsigned short*)((char*)d_ws + 2097152);

  int base = haveWoutBf ? 0 : 8000;
  k_prep<<<8576-base,256,0,stream>>>(Wout, woutbf, W2, WT2, W3, WT3, x, embed, Xm, base);
  k_cur1<<<128,256,0,stream>>>(x, embed, W1, b1, cur1);

  k_scan1<<<128,64,0,stream>>>(cur1, rec1, mem1);
  k_gemm_f32<<<2560,256,0,stream>>>(rec1, WT2, b2, curbuf);
  k_scan23<false><<<128,64,0,stream>>>(curbuf, rec2, mem2, nullptr);
  k_gemm_f32<<<2560,256,0,stream>>>(rec2, WT3, b3, curbuf);
  k_scan23<true><<<128,64,0,stream>>>(curbuf, rec3, mem3, pooled);

  k_mmean<<<896,256,0,stream>>>(rec1, M1);
  k_mmean<<<896,256,0,stream>>>(rec2, M2);
  k_mmean<<<896,256,0,stream>>>(rec3, M3);
  k_d1<<<256,128,0,stream>>>(M1, Xm, d1);
  k_d23<<<256,256,0,stream>>>(M2, M1, d2);
  k_d23<<<256,256,0,stream>>>(M3, M2, d3);

  if (haveWoutBf)
    k_gemm_out<true ><<<8000,256,0,stream>>>(pooled, woutbf, nullptr, bout, out);
  else
    k_gemm_out<false><<<8000,256,0,stream>>>(pooled, nullptr, Wout,  bout, out);
}

// Round 3
// 1905.689 us; speedup vs baseline: 1.0317x; 1.0084x over previous
//
#include <hip/hip_runtime.h>
#include <cstdint>

#define T_STEPS 20
#define S_LEN   128
#define BATCH   32
#define HID     256
#define EMB     128
#define VOCAB   32000
#define NSTEP   (S_LEN*T_STEPS)    /* 2560 */
#define NBROWS  (NSTEP*BATCH)      /* 81920 */

typedef __bf16 bf8   __attribute__((ext_vector_type(8)));
typedef float  f32x4 __attribute__((ext_vector_type(4)));

static __device__ __forceinline__ unsigned short f2bf_u(float f){
  unsigned int u = __builtin_bit_cast(unsigned int, f);
  u = u + 0x7FFFu + ((u >> 16) & 1u);
  return (unsigned short)(u >> 16);
}

// ---------------- fused prep: bf16(Wout) | W2^T | W3^T | Xm ----------------
// blk layout: [0,8000) bf16 convert, [8000,8256) WT2, [8256,8512) WT3, [8512,8576) Xm
__global__ __launch_bounds__(256) void k_prep(const float* __restrict__ Wout, unsigned short* __restrict__ woutbf,
                                              const float* __restrict__ W2, float* __restrict__ WT2,
                                              const float* __restrict__ W3, float* __restrict__ WT3,
                                              const int* __restrict__ x, const float* __restrict__ embed,
                                              float* __restrict__ Xm, int base){
  int blk = blockIdx.x + base;
  int t = threadIdx.x;
  if (blk < 8000){
    int i = blk*256 + t;                 // < 2048000 exactly
    float4 v = ((const float4*)Wout)[i];
    ushort4 o; o.x=f2bf_u(v.x); o.y=f2bf_u(v.y); o.z=f2bf_u(v.z); o.w=f2bf_u(v.w);
    ((ushort4*)woutbf)[i] = o;
  } else if (blk < 8256){
    int i = (blk-8000)*256 + t;          // 65536
    int n = i >> 8, k = i & 255;
    WT2[k*HID + n] = W2[i];
  } else if (blk < 8512){
    int i = (blk-8256)*256 + t;
    int n = i >> 8, k = i & 255;
    WT3[k*HID + n] = W3[i];
  } else {
    int s = (blk-8512)*2 + (t >> 7);     // 64 blocks x 2 s
    int i = t & 127;
    float acc = 0.f;
    for (int b=0;b<BATCH;b++){
      int tok = x[b*S_LEN + s];
      acc += embed[(size_t)tok*EMB + i];
    }
    Xm[s*EMB + i] = acc * (1.0f/32.0f);
  }
}

// cur1[(s*B+b)][h] = fma-chain_e( embed[x[b][s]][e] * W1[h][e] ) + b1[h]  (ascending e, f32 FMA)
__global__ __launch_bounds__(256) void k_cur1(const int* __restrict__ x, const float* __restrict__ embed,
                                              const float* __restrict__ W1, const float* __restrict__ b1,
                                              float* __restrict__ cur1){
  __shared__ float xe[BATCH*EMB];  // [b][e]
  int s = blockIdx.x, t = threadIdx.x;
  for (int i=t; i<BATCH*EMB/4; i+=256){
    int b = i >> 5, e4 = i & 31;
    int tok = x[b*S_LEN + s];
    ((float4*)xe)[i] = ((const float4*)(embed + (size_t)tok*EMB))[e4];
  }
  __syncthreads();
  int h = t;
  float acc[BATCH];
  #pragma unroll
  for (int b=0;b<BATCH;b++) acc[b]=0.f;
  for (int ec=0; ec<4; ec++){
    float wd[32];
    #pragma unroll
    for (int e4=0;e4<8;e4++){
      float4 w = *(const float4*)(W1 + (size_t)h*EMB + ec*32 + e4*4);
      wd[e4*4+0]=w.x; wd[e4*4+1]=w.y; wd[e4*4+2]=w.z; wd[e4*4+3]=w.w;
    }
    #pragma unroll
    for (int b=0;b<BATCH;b++){
      #pragma unroll
      for (int e=0;e<32;e++)
        acc[b] = fmaf(xe[b*EMB + ec*32 + e], wd[e], acc[b]);   // ascending k, single chain
    }
  }
  float bi = b1[h];
  #pragma unroll
  for (int b=0;b<BATCH;b++)
    cur1[(size_t)(s*BATCH + b)*HID + h] = __fadd_rn(acc[b], bi);
}

// ---------------- LIF scans: np-exact f32 op order (mul, add, sub; no FMA) ----------------
__global__ __launch_bounds__(64) void k_scan1(const float* __restrict__ cur1, float* __restrict__ rec,
                                              float* __restrict__ memout){
  int bid = blockIdx.x; int b = bid >> 2; int hq = bid & 3;
  int h = hq*64 + threadIdx.x;
  const int strN = BATCH*HID;
  const float* cp = cur1 + b*HID + h;
  float* rp = rec + b*HID + h;
  float mem = 0.f;
  float c = cp[0];
  for (int s=0; s<S_LEN; s++){
    float cn = (s+1 < S_LEN) ? cp[(size_t)(s+1)*strN] : 0.f;   // prefetch next token
    #pragma unroll
    for (int t=0;t<T_STEPS;t++){
      float reset = (mem > 1.0f) ? 1.0f : 0.0f;
      float tm = __fmul_rn(0.85f, mem);
      tm = __fadd_rn(tm, c);
      mem = __fsub_rn(tm, reset);
      rp[(size_t)(s*T_STEPS + t)*strN] = (mem > 1.0f) ? 1.0f : 0.0f;
    }
    c = cn;
  }
  memout[b*HID + h] = mem;
}

// layers 2/3: cur per step (bias already folded, rounded, in GEMM); POOL emits bf16 pooled means
template<bool POOL>
__global__ __launch_bounds__(64) void k_scan23(const float* __restrict__ cur,
                                               float* __restrict__ rec, float* __restrict__ memout,
                                               unsigned short* __restrict__ pooled){
  int bid = blockIdx.x; int b = bid >> 2; int hq = bid & 3;
  int h = hq*64 + threadIdx.x;
  const int strN = BATCH*HID;
  const float* cp = cur + b*HID + h;
  float* rp = rec + b*HID + h;
  unsigned short* pp = POOL ? (pooled + (size_t)b*S_LEN*HID + h) : nullptr;
  float mem = 0.f;
  float ps = 0.f;
  int tc = 0, sTok = 0;
  float cA[16], cB[16];

  auto step = [&](float c, int n){
    float reset = (mem > 1.0f) ? 1.0f : 0.0f;
    float tm = __fmul_rn(0.85f, mem);
    tm = __fadd_rn(tm, c);
    mem = __fsub_rn(tm, reset);
    float spk = (mem > 1.0f) ? 1.f : 0.f;
    rp[(size_t)n*strN] = spk;
    if constexpr (POOL){
      ps += spk;                       // exact integer count <= 20
      if (++tc == T_STEPS){
        pp[(size_t)sTok*HID] = f2bf_u(__fdiv_rn(ps, 20.0f));   // np mean = sum/20, correctly rounded
        ps = 0.f; tc = 0; ++sTok;
      }
    }
  };

  #pragma unroll
  for (int j=0;j<16;j++) cA[j] = cp[(size_t)j*strN];
  for (int n0=0; n0<NSTEP; n0+=32){
    #pragma unroll
    for (int j=0;j<16;j++) cB[j] = cp[(size_t)(n0+16+j)*strN];
    #pragma unroll
    for (int j=0;j<16;j++) step(cA[j], n0+j);
    if (n0+32 < NSTEP){
      #pragma unroll
      for (int j=0;j<16;j++) cA[j] = cp[(size_t)(n0+32+j)*strN];
    }
    #pragma unroll
    for (int j=0;j<16;j++) step(cB[j], n0+16+j);
  }
  memout[b*HID + h] = mem;
}

// ---------------- np/BLAS-exact f32 GEMM ----------------
// cur[m][n] = ( fma-chain_{k=0..255} spk[m][k]*W[n][k] )  +rn bias[n]
// Bit-identical op order (single ascending-k FMA chain per element).
// XCD-ownership swizzle: x=bid&7, i=bid>>3; w=x*320+i -> each XCD owns a
// contiguous m-panel range; A-panel fetched by ONE XCD-L2 only.
__global__ __launch_bounds__(256) void k_gemm_f32(const float* __restrict__ spk,
                                                  const float* __restrict__ WT,   // [256][256] transposed
                                                  const float* __restrict__ bias,
                                                  float* __restrict__ curo){
  __shared__ float As[256*36];        // 256 rows x 32 k, padded to 36 floats
  int bid = blockIdx.x;               // 2560
  int x = bid & 7, i = bid >> 3;
  int w = x*320 + i;
  int m0 = (w >> 3) * 256;
  int n0 = (w & 7) * 32;
  int t  = threadIdx.x;
  float acc[32];
  #pragma unroll
  for (int n=0;n<32;n++) acc[n]=0.f;

  for (int kc=0; kc<8; kc++){
    __syncthreads();                  // readers of previous tile done
    #pragma unroll
    for (int j=0;j<8;j++){
      int id = t + j*256;             // 2048 float4 = 256 rows x 32 k
      int r = id >> 3, c4 = id & 7;   // 8 lanes per row -> 128 B coalesced
      float4 v = *(const float4*)(spk + (size_t)(m0 + r)*HID + kc*32 + c4*4);
      *(float4*)(As + r*36 + c4*4) = v;
    }
    __syncthreads();
    const float* wrow = WT + (size_t)(kc*32)*HID + n0;
    #pragma unroll
    for (int g=0; g<8; g++){
      float4 sv4 = *(const float4*)(As + t*36 + g*4);   // own row, 4 k's, b128
      #pragma unroll
      for (int j=0;j<4;j++){
        float sv = (j==0)?sv4.x:(j==1)?sv4.y:(j==2)?sv4.z:sv4.w;
        const float* wt = wrow + (size_t)(g*4+j)*HID;   // wave-uniform -> s_load
        #pragma unroll
        for (int n=0;n<32;n++)
          acc[n] = fmaf(sv, wt[n], acc[n]);             // ascending k, single chain
      }
    }
  }
  float* op = curo + (size_t)(m0 + t)*HID + n0;
  #pragma unroll
  for (int n=0;n<32;n++) op[n] = __fadd_rn(acc[n], bias[n0+n]);
}

// ---------------- bf16 MFMA out-GEMM: out[4096][32000] = pooled[4096][256] @ Wout^T + bout ----------------
// XCD swizzle keeps B-panel's 32 m-sharers on one XCD. Epilogue transposes
// C-fragments through LDS (reusing As) so global stores are full-line
// contiguous float4 NT stores: fixes 3.3x write amplification + L2 thrash.
template<bool BF16B>
__global__ __launch_bounds__(256,2) void k_gemm_out(const unsigned short* __restrict__ Abf,
                                                    const unsigned short* __restrict__ Bbf,
                                                    const float* __restrict__ Bf32,
                                                    const float* __restrict__ bout,
                                                    float* __restrict__ outp){
  __shared__ __align__(16) unsigned short As[128*72];   // 18 KB; reused as 32x132 f32 C-tile
  __shared__ __align__(16) unsigned short Bs[128*72];
  int bid = blockIdx.x;               // 8000
  int xc = bid & 7, ib = bid >> 3;
  int w = xc*1000 + ib;
  int ntile = w >> 5;
  int mtile = w & 31;
  int m0 = mtile*128, n0 = ntile*128;
  int tid = threadIdx.x;
  int lane = tid & 63, wave = tid >> 6;
  int wm = wave >> 1, wn = wave & 1;
  int lm = lane & 15, quad = lane >> 4;
  f32x4 acc[4][4] = {};

  for (int kt=0; kt<4; kt++){
    int k0 = kt*64;
    uint4 avb[4];
    #pragma unroll
    for (int i=0;i<4;i++){
      int id = tid + i*256; int r = id>>3, c16 = id&7;
      avb[i] = *(const uint4*)(Abf + (size_t)(m0 + r)*HID + k0 + c16*8);
    }
    uint4 bvb[4]; float4 bvf[8];
    if (BF16B){
      #pragma unroll
      for (int i=0;i<4;i++){
        int id = tid + i*256; int r = id>>3, c16 = id&7;
        bvb[i] = *(const uint4*)(Bbf + (size_t)(n0 + r)*HID + k0 + c16*8);
      }
    } else {
      #pragma unroll
      for (int i=0;i<8;i++){
        int id = tid + i*256; int r = id>>4, c4 = id&15;
        bvf[i] = *(const float4*)(Bf32 + (size_t)(n0 + r)*HID + k0 + c4*4);
      }
    }
    __syncthreads();
    #pragma unroll
    for (int i=0;i<4;i++){
      int id = tid + i*256; int r = id>>3, c16 = id&7;
      *(uint4*)(As + r*72 + c16*8) = avb[i];
    }
    if (BF16B){
      #pragma unroll
      for (int i=0;i<4;i++){
        int id = tid + i*256; int r = id>>3, c16 = id&7;
        *(uint4*)(Bs + r*72 + c16*8) = bvb[i];
      }
    } else {
      #pragma unroll
      for (int i=0;i<8;i++){
        int id = tid + i*256; int r = id>>4, c4 = id&15;
        ushort4 o; o.x=f2bf_u(bvf[i].x); o.y=f2bf_u(bvf[i].y); o.z=f2bf_u(bvf[i].z); o.w=f2bf_u(bvf[i].w);
        *(ushort4*)(Bs + r*72 + c4*4) = o;
      }
    }
    __syncthreads();
    bf8 af[4][2], bfr[4][2];
    #pragma unroll
    for (int mt=0;mt<4;mt++)
      #pragma unroll
      for (int kk=0;kk<2;kk++)
        af[mt][kk] = *(const bf8*)(As + (wm*64 + mt*16 + lm)*72 + kk*32 + quad*8);
    #pragma unroll
    for (int nt=0;nt<4;nt++)
      #pragma unroll
      for (int kk=0;kk<2;kk++)
        bfr[nt][kk] = *(const bf8*)(Bs + (wn*64 + nt*16 + lm)*72 + kk*32 + quad*8);
    #pragma unroll
    for (int mt=0;mt<4;mt++)
      #pragma unroll
      for (int nt=0;nt<4;nt++){
        acc[mt][nt] = __builtin_amdgcn_mfma_f32_16x16x32_bf16(af[mt][0], bfr[nt][0], acc[mt][nt], 0,0,0);
        acc[mt][nt] = __builtin_amdgcn_mfma_f32_16x16x32_bf16(af[mt][1], bfr[nt][1], acc[mt][nt], 0,0,0);
      }
    __syncthreads();
  }

  // ---- transposed epilogue: fragment -> LDS row-tile -> full-line NT stores ----
  float bo[4];
  #pragma unroll
  for (int nt=0;nt<4;nt++) bo[nt] = bout[n0 + wn*64 + nt*16 + lm];
  float* Cs = (float*)As;             // 32 rows x 132 floats (padded) = 16.9 KB
  #pragma unroll
  for (int mt=0;mt<4;mt++){
    #pragma unroll
    for (int nt=0;nt<4;nt++)
      #pragma unroll
      for (int rr=0;rr<4;rr++)
        Cs[(wm*16 + quad*4 + rr)*132 + wn*64 + nt*16 + lm] = acc[mt][nt][rr] + bo[nt];
    __syncthreads();
    #pragma unroll
    for (int f=0; f<4; f++){
      int id = tid + f*256;           // 1024 float4 = 32 rows x 128 cols
      int lr = id >> 5, c4 = id & 31;
      int r = m0 + (lr>>4)*64 + mt*16 + (lr&15);
      f32x4 val = *(const f32x4*)(Cs + lr*132 + c4*4);
      __builtin_nontemporal_store(val, (f32x4*)(outp + (size_t)r*VOCAB + n0 + c4*4));
    }
    __syncthreads();
  }
}

// ---------------- STDP ----------------
__global__ void k_mmean(const float* __restrict__ rec, float* __restrict__ M){
  int m = blockIdx.x, o = threadIdx.x;
  int s = m / 7, j = m - 7*s;
  int n = s*T_STEPS + j*3;
  const float* rp = rec + (size_t)n*BATCH*HID + o;
  float acc = 0.f;
  #pragma unroll
  for (int b=0;b<BATCH;b++) acc += rp[b*HID];
  M[m*HID + o] = acc * (1.0f/32.0f);   // exact: integer count / 32
}

__global__ void k_d1(const float* __restrict__ M1, const float* __restrict__ Xm, float* __restrict__ d1){
  __shared__ float col[896];
  int o = blockIdx.x, i = threadIdx.x; // 128 thr
  for (int m=i; m<896; m+=128) col[m] = M1[m*HID + o];
  __syncthreads();
  float acc = 0.f;
  for (int s=0;s<S_LEN;s++){
    float xv = Xm[s*EMB + i];
    float cs = 0.f;
    #pragma unroll
    for (int j=0;j<7;j++) cs += col[s*7+j];
    acc += cs * xv;
  }
  d1[o*EMB + i] = -1.5e-5f * acc;
}

__global__ void k_d23(const float* __restrict__ Mpost, const float* __restrict__ Mpre, float* __restrict__ d){
  __shared__ float col[896];
  int o = blockIdx.x, i = threadIdx.x; // 256 thr
  for (int m=i; m<896; m+=256) col[m] = Mpost[m*HID + o];
  __syncthreads();
  float acc = 0.f;
  for (int m=0;m<896;m++) acc += col[m] * Mpre[m*HID + i];
  d[o*HID + i] = -1.5e-5f * acc;
}

// ---------------- launch ----------------
extern "C" void kernel_launch(void* const* d_in, const int* in_sizes, int n_in,
                              void* d_out, int out_size, void* d_ws, size_t ws_size,
                              hipStream_t stream){
  const int*   x     = (const int*)d_in[0];
  const float* embed = (const float*)d_in[1];
  const float* W1    = (const float*)d_in[2];
  const float* b1    = (const float*)d_in[3];
  const float* W2    = (const float*)d_in[4];
  const float* b2    = (const float*)d_in[5];
  const float* W3    = (const float*)d_in[6];
  const float* b3    = (const float*)d_in[7];
  const float* Wout  = (const float*)d_in[8];
  const float* bout  = (const float*)d_in[9];
  float* out = (float*)d_out;

  // output regions (float offsets)
  float* mem1 = out + 131072000;
  float* mem2 = out + 131080192;
  float* mem3 = out + 131088384;
  float* d1   = out + 131096576;
  float* d2   = out + 131129344;
  float* d3   = out + 131194880;
  float* rec1 = out + 131260416;
  float* rec2 = out + 152231936;
  float* rec3 = out + 173203456;

  // scratch carved from the out[B,S,V] region (dead until final GEMM overwrites it)
  float* curbuf = out + 0;                       // 81920*256 f32
  float* cur1   = out + 20971520;                // 4096*256
  float* Xm     = out + 22020096;                // 16384
  float* M1     = out + 22036480;                // 229376
  float* M2     = out + 22265856;
  float* M3     = out + 22495232;
  float* WT2    = out + 22724608;                // 65536
  float* WT3    = out + 22790144;                // end 22855680 < 131072000

  // ws: pooled bf16 (2 MB) + optional Wout bf16 (16.4 MB)
  unsigned short* pooled = (unsigned short*)d_ws;
  bool haveWoutBf = ws_size >= (size_t)(2097152 + 16384000);
  unsigned short* woutbf = (unsigned short*)((char*)d_ws + 2097152);

  int base = haveWoutBf ? 0 : 8000;
  k_prep<<<8576-base,256,0,stream>>>(Wout, woutbf, W2, WT2, W3, WT3, x, embed, Xm, base);
  k_cur1<<<128,256,0,stream>>>(x, embed, W1, b1, cur1);

  k_scan1<<<128,64,0,stream>>>(cur1, rec1, mem1);
  k_gemm_f32<<<2560,256,0,stream>>>(rec1, WT2, b2, curbuf);
  k_scan23<false><<<128,64,0,stream>>>(curbuf, rec2, mem2, nullptr);
  k_gemm_f32<<<2560,256,0,stream>>>(rec2, WT3, b3, curbuf);
  k_scan23<true><<<128,64,0,stream>>>(curbuf, rec3, mem3, pooled);

  k_mmean<<<896,256,0,stream>>>(rec1, M1);
  k_mmean<<<896,256,0,stream>>>(rec2, M2);
  k_mmean<<<896,256,0,stream>>>(rec3, M3);
  k_d1<<<256,128,0,stream>>>(M1, Xm, d1);
  k_d23<<<256,256,0,stream>>>(M2, M1, d2);
  k_d23<<<256,256,0,stream>>>(M3, M2, d3);

  if (haveWoutBf)
    k_gemm_out<true ><<<8000,256,0,stream>>>(pooled, woutbf, nullptr, bout, out);
  else
    k_gemm_out<false><<<8000,256,0,stream>>>(pooled, nullptr, Wout,  bout, out);
}